// Round 1
// baseline (903.090 us; speedup 1.0000x reference)
//
#include <hip/hip_runtime.h>

#define NN 100000
#define EE 1600000

// ---------------- CSR build ----------------

__global__ void init_counts(int* __restrict__ counts, int* __restrict__ fill) {
  int i = blockIdx.x * 256 + threadIdx.x;
  if (i < NN) { counts[i] = 1; fill[i] = 0; }   // 1 = self loop
}

__global__ void count_edges(const int* __restrict__ dst, int* __restrict__ counts) {
  int e = blockIdx.x * 256 + threadIdx.x;
  if (e < EE) atomicAdd(&counts[dst[e]], 1);
}

// single-block exclusive scan, 1024 threads x 4 elems per iter
__global__ void scan_offsets(const int* __restrict__ counts, int* __restrict__ offsets) {
  __shared__ int wsums[16];
  __shared__ int carryS;
  int tid = threadIdx.x, lane = tid & 63, wid = tid >> 6;
  if (tid == 0) carryS = 0;
  __syncthreads();
  for (int base = 0; base < NN; base += 4096) {
    int i0 = base + tid * 4;
    int4 v = {0, 0, 0, 0};
    if (i0 < NN) v = *(const int4*)&counts[i0];   // NN % 4 == 0, so all-or-none
    int tsum = v.x + v.y + v.z + v.w;
    int x = tsum;
    #pragma unroll
    for (int d = 1; d < 64; d <<= 1) { int y = __shfl_up(x, d); if (lane >= d) x += y; }
    if (lane == 63) wsums[wid] = x;
    __syncthreads();
    if (tid < 16) {
      int s = wsums[tid];
      #pragma unroll
      for (int d = 1; d < 16; d <<= 1) { int y = __shfl_up(s, d); if (tid >= d) s += y; }
      wsums[tid] = s;
    }
    __syncthreads();
    int carry = carryS;
    int wbase = (wid == 0) ? 0 : wsums[wid - 1];
    int excl = carry + wbase + (x - tsum);
    if (i0 < NN) {
      int4 o;
      o.x = excl;
      o.y = o.x + v.x;
      o.z = o.y + v.y;
      o.w = o.z + v.z;
      *(int4*)&offsets[i0] = o;
    }
    int total = wsums[15];
    __syncthreads();
    if (tid == 0) carryS = carry + total;
    __syncthreads();
  }
  if (tid == 0) offsets[NN] = carryS;
}

__global__ void fill_edges(const int* __restrict__ ei, const int* __restrict__ offsets,
                           int* __restrict__ fill, int* __restrict__ srcs) {
  int idx = blockIdx.x * 256 + threadIdx.x;
  if (idx >= EE + NN) return;
  int s, d;
  if (idx < EE) { s = ei[idx]; d = ei[EE + idx]; }
  else          { s = d = idx - EE; }            // self loop
  int p = atomicAdd(&fill[d], 1);
  srcs[offsets[d] + p] = s;
}

// ---------------- transform: h = x @ W, alpha_s = h.a_src, alpha_d = h.a_dst ----------------
// block: 256 threads, 128 rows x 128 cols tile; thread = 4 rows x 16 cols.

__launch_bounds__(256, 1)
__global__ void transform_kernel(const float* __restrict__ x, const float* __restrict__ W,
                                 const float* __restrict__ a_src, const float* __restrict__ a_dst,
                                 float* __restrict__ h, float* __restrict__ alphaS,
                                 float* __restrict__ alphaD) {
  __shared__ float Ws[128 * 128];   // granule-swizzled: granule s -> slot (s&3)*8 + (s>>2)
  __shared__ float Xs[128 * 129];   // pitch 129: conflict-free scalar broadcasts
  int tid = threadIdx.x;
  int r0 = blockIdx.x * 128;

  // stage W (swizzled), coalesced float4 reads
  #pragma unroll
  for (int q = 0; q < 16; ++q) {
    int fi = q * 1024 + tid * 4;
    int k = fi >> 7, c = fi & 127;
    float4 v = *(const float4*)&W[k * 128 + c];
    int s = c >> 2;
    int slot = ((s & 3) << 3) + (s >> 2);
    *(float4*)&Ws[k * 128 + slot * 4] = v;
  }
  // stage X tile (scalar LDS writes; pitch 129 rows are only 4B-aligned)
  #pragma unroll
  for (int q = 0; q < 16; ++q) {
    int fi = q * 1024 + tid * 4;
    int r = fi >> 7, c = fi & 127;
    int R = r0 + r;
    float4 v = {0.f, 0.f, 0.f, 0.f};
    if (R < NN) v = *(const float4*)&x[(size_t)R * 128 + c];
    float* p = &Xs[r * 129 + c];
    p[0] = v.x; p[1] = v.y; p[2] = v.z; p[3] = v.w;
  }
  __syncthreads();

  int g  = tid & 7;    // col group: cols g*16 .. g*16+15
  int rg = tid >> 3;   // row group: rows rg*4 .. rg*4+3
  float acc[4][16];
  #pragma unroll
  for (int j = 0; j < 4; ++j)
    #pragma unroll
    for (int ii = 0; ii < 16; ++ii) acc[j][ii] = 0.f;

  const int xbase = rg * 4 * 129;
  for (int k = 0; k < 128; ++k) {
    const float4* wr = (const float4*)&Ws[k * 128];
    float4 w0 = wr[g];
    float4 w1 = wr[8 + g];
    float4 w2 = wr[16 + g];
    float4 w3 = wr[24 + g];
    #pragma unroll
    for (int j = 0; j < 4; ++j) {
      float xv = Xs[xbase + j * 129 + k];
      acc[j][0]  = fmaf(xv, w0.x, acc[j][0]);
      acc[j][1]  = fmaf(xv, w0.y, acc[j][1]);
      acc[j][2]  = fmaf(xv, w0.z, acc[j][2]);
      acc[j][3]  = fmaf(xv, w0.w, acc[j][3]);
      acc[j][4]  = fmaf(xv, w1.x, acc[j][4]);
      acc[j][5]  = fmaf(xv, w1.y, acc[j][5]);
      acc[j][6]  = fmaf(xv, w1.z, acc[j][6]);
      acc[j][7]  = fmaf(xv, w1.w, acc[j][7]);
      acc[j][8]  = fmaf(xv, w2.x, acc[j][8]);
      acc[j][9]  = fmaf(xv, w2.y, acc[j][9]);
      acc[j][10] = fmaf(xv, w2.z, acc[j][10]);
      acc[j][11] = fmaf(xv, w2.w, acc[j][11]);
      acc[j][12] = fmaf(xv, w3.x, acc[j][12]);
      acc[j][13] = fmaf(xv, w3.y, acc[j][13]);
      acc[j][14] = fmaf(xv, w3.z, acc[j][14]);
      acc[j][15] = fmaf(xv, w3.w, acc[j][15]);
    }
  }

  // epilogue: store h, compute alpha partials and reduce across the 8 col-group lanes
  int c0 = g * 16;
  float as[16], ad[16];
  #pragma unroll
  for (int ii = 0; ii < 16; ++ii) { as[ii] = a_src[c0 + ii]; ad[ii] = a_dst[c0 + ii]; }

  #pragma unroll
  for (int j = 0; j < 4; ++j) {
    int R = r0 + rg * 4 + j;
    float ps = 0.f, pd = 0.f;
    #pragma unroll
    for (int ii = 0; ii < 16; ++ii) {
      ps = fmaf(acc[j][ii], as[ii], ps);
      pd = fmaf(acc[j][ii], ad[ii], pd);
    }
    #pragma unroll
    for (int mdl = 1; mdl < 8; mdl <<= 1) {
      ps += __shfl_xor(ps, mdl);
      pd += __shfl_xor(pd, mdl);
    }
    if (R < NN) {
      #pragma unroll
      for (int i = 0; i < 4; ++i) {
        float4 st = {acc[j][i * 4], acc[j][i * 4 + 1], acc[j][i * 4 + 2], acc[j][i * 4 + 3]};
        *(float4*)&h[(size_t)R * 128 + c0 + i * 4] = st;
      }
      if (g == 0) { alphaS[R] = ps; alphaD[R] = pd; }
    }
  }
}

// ---------------- aggregation: one wave per dst node ----------------

__launch_bounds__(256)
__global__ void agg_kernel(const float* __restrict__ h, const float* __restrict__ alphaS,
                           const float* __restrict__ alphaD, const int* __restrict__ offsets,
                           const int* __restrict__ srcs, const float* __restrict__ bias,
                           float* __restrict__ out, int doRelu) {
  int lane = threadIdx.x & 63;
  int node = (blockIdx.x * 256 + threadIdx.x) >> 6;
  if (node >= NN) return;
  int beg = offsets[node], end = offsets[node + 1];
  float aD = alphaD[node];

  // pass 1: online softmax (max + sum) over this node's edges, 64-lane strided
  float m = -1e30f, ssum = 0.f;
  for (int j = beg + lane; j < end; j += 64) {
    int s = srcs[j];
    float e = alphaS[s] + aD;
    e = (e >= 0.f) ? e : 0.2f * e;
    if (e > m) { ssum = ssum * __expf(m - e) + 1.f; m = e; }
    else       { ssum += __expf(e - m); }
  }
  #pragma unroll
  for (int d2 = 1; d2 < 64; d2 <<= 1) {
    float mo = __shfl_xor(m, d2), so = __shfl_xor(ssum, d2);
    float mn = fmaxf(m, mo);
    ssum = ssum * __expf(m - mn) + so * __expf(mo - mn);
    m = mn;
  }
  float inv = 1.f / ssum;

  // pass 2: weighted gather-accumulate; all 64 lanes cooperate per edge (float2 per lane)
  float accx = 0.f, accy = 0.f;
  for (int j0 = beg; j0 < end; j0 += 64) {
    int j = j0 + lane;
    int cnt = min(64, end - j0);
    int s = 0; float wgt = 0.f;
    if (j < end) {
      s = srcs[j];
      float e = alphaS[s] + aD;
      e = (e >= 0.f) ? e : 0.2f * e;
      wgt = __expf(e - m) * inv;
    }
    for (int jj = 0; jj < cnt; ++jj) {
      int sv   = __shfl(s, jj);
      float wv = __shfl(wgt, jj);
      const float2 hp = *(const float2*)&h[(size_t)sv * 128 + lane * 2];
      accx = fmaf(wv, hp.x, accx);
      accy = fmaf(wv, hp.y, accy);
    }
  }

  float ox = accx + bias[lane * 2];
  float oy = accy + bias[lane * 2 + 1];
  if (doRelu) { ox = fmaxf(ox, 0.f); oy = fmaxf(oy, 0.f); }
  float2 o = {ox, oy};
  *(float2*)&out[(size_t)node * 128 + lane * 2] = o;
}

// ---------------- launch ----------------

extern "C" void kernel_launch(void* const* d_in, const int* in_sizes, int n_in,
                              void* d_out, int out_size, void* d_ws, size_t ws_size,
                              hipStream_t stream) {
  const float* x   = (const float*)d_in[0];
  const int*   ei  = (const int*)d_in[1];
  const float* W0  = (const float*)d_in[2];
  const float* as0 = (const float*)d_in[3];
  const float* ad0 = (const float*)d_in[4];
  const float* b0  = (const float*)d_in[5];
  const float* W1  = (const float*)d_in[6];
  const float* as1 = (const float*)d_in[7];
  const float* ad1 = (const float*)d_in[8];
  const float* b1  = (const float*)d_in[9];
  const float* W2  = (const float*)d_in[10];
  const float* as2 = (const float*)d_in[11];
  const float* ad2 = (const float*)d_in[12];
  const float* b2  = (const float*)d_in[13];
  float* out = (float*)d_out;

  float* h      = (float*)d_ws;                    // N*128
  float* alphaS = h + (size_t)NN * 128;            // N
  float* alphaD = alphaS + NN;                     // N
  int*   counts = (int*)(alphaD + NN);             // N
  int*   offsets = counts + NN;                    // N+1
  int*   fill    = offsets + NN + 1;               // N
  int*   srcs    = fill + NN;                      // E+N

  // CSR by destination (deterministic work each call)
  init_counts<<<(NN + 255) / 256, 256, 0, stream>>>(counts, fill);
  count_edges<<<(EE + 255) / 256, 256, 0, stream>>>(ei + EE, counts);
  scan_offsets<<<1, 1024, 0, stream>>>(counts, offsets);
  fill_edges<<<(EE + NN + 255) / 256, 256, 0, stream>>>(ei, offsets, fill, srcs);

  const int tgrid = (NN + 127) / 128;
  const int agrid = (NN + 3) / 4;

  // layer 0: x -> h; agg -> out (acts as activation buffer)
  transform_kernel<<<tgrid, 256, 0, stream>>>(x, W0, as0, ad0, h, alphaS, alphaD);
  agg_kernel<<<agrid, 256, 0, stream>>>(h, alphaS, alphaD, offsets, srcs, b0, out, 1);
  // layer 1: out -> h; agg -> out
  transform_kernel<<<tgrid, 256, 0, stream>>>(out, W1, as1, ad1, h, alphaS, alphaD);
  agg_kernel<<<agrid, 256, 0, stream>>>(h, alphaS, alphaD, offsets, srcs, b1, out, 1);
  // layer 2: out -> h; agg -> out (no relu)
  transform_kernel<<<tgrid, 256, 0, stream>>>(out, W2, as2, ad2, h, alphaS, alphaD);
  agg_kernel<<<agrid, 256, 0, stream>>>(h, alphaS, alphaD, offsets, srcs, b2, out, 0);
}

// Round 2
// 698.745 us; speedup vs baseline: 1.2924x; 1.2924x over previous
//
#include <hip/hip_runtime.h>

#define NN 100000
#define EE 1600000

static __device__ __forceinline__ unsigned short f2bf(float f) {
  unsigned u = __float_as_uint(f);
  u += 0x7fffu + ((u >> 16) & 1u);   // round-to-nearest-even
  return (unsigned short)(u >> 16);
}

// ---------------- CSR build ----------------

__global__ void init_counts(int* __restrict__ counts, int* __restrict__ fill) {
  int i = blockIdx.x * 256 + threadIdx.x;
  if (i < NN) { counts[i] = 1; fill[i] = 0; }   // 1 = self loop
}

__global__ void count_edges(const int* __restrict__ dst, int* __restrict__ counts) {
  int e = blockIdx.x * 256 + threadIdx.x;
  if (e < EE) atomicAdd(&counts[dst[e]], 1);
}

// single-block exclusive scan, 1024 threads x 4 elems per iter
__global__ void scan_offsets(const int* __restrict__ counts, int* __restrict__ offsets) {
  __shared__ int wsums[16];
  __shared__ int carryS;
  int tid = threadIdx.x, lane = tid & 63, wid = tid >> 6;
  if (tid == 0) carryS = 0;
  __syncthreads();
  for (int base = 0; base < NN; base += 4096) {
    int i0 = base + tid * 4;
    int4 v = {0, 0, 0, 0};
    if (i0 < NN) v = *(const int4*)&counts[i0];   // NN % 4 == 0, so all-or-none
    int tsum = v.x + v.y + v.z + v.w;
    int x = tsum;
    #pragma unroll
    for (int d = 1; d < 64; d <<= 1) { int y = __shfl_up(x, d); if (lane >= d) x += y; }
    if (lane == 63) wsums[wid] = x;
    __syncthreads();
    if (tid < 16) {
      int s = wsums[tid];
      #pragma unroll
      for (int d = 1; d < 16; d <<= 1) { int y = __shfl_up(s, d); if (tid >= d) s += y; }
      wsums[tid] = s;
    }
    __syncthreads();
    int carry = carryS;
    int wbase = (wid == 0) ? 0 : wsums[wid - 1];
    int excl = carry + wbase + (x - tsum);
    if (i0 < NN) {
      int4 o;
      o.x = excl;
      o.y = o.x + v.x;
      o.z = o.y + v.y;
      o.w = o.z + v.z;
      *(int4*)&offsets[i0] = o;
    }
    int total = wsums[15];
    __syncthreads();
    if (tid == 0) carryS = carry + total;
    __syncthreads();
  }
  if (tid == 0) offsets[NN] = carryS;
}

__global__ void fill_edges(const int* __restrict__ ei, const int* __restrict__ offsets,
                           int* __restrict__ fill, int* __restrict__ srcs) {
  int idx = blockIdx.x * 256 + threadIdx.x;
  if (idx >= EE + NN) return;
  int s, d;
  if (idx < EE) { s = ei[idx]; d = ei[EE + idx]; }
  else          { s = d = idx - EE; }            // self loop
  int p = atomicAdd(&fill[d], 1);
  srcs[offsets[d] + p] = s;
}

// ---------------- transform: h = x @ W, alpha_s = h.a_src, alpha_d = h.a_dst ----------------
// 256 threads, 128x128 tile, thread = 4 rows x 16 cols. Only W staged in LDS (64KB ->
// 2 blocks/CU); x read directly from global (linear per-row float4 walk, L1-served).

template<bool BF16OUT>
__launch_bounds__(256, 2)
__global__ void transform_kernel(const float* __restrict__ x, const float* __restrict__ W,
                                 const float* __restrict__ a_src, const float* __restrict__ a_dst,
                                 float* __restrict__ h, unsigned short* __restrict__ hb,
                                 float* __restrict__ alphaS, float* __restrict__ alphaD) {
  __shared__ float Ws[128 * 128];   // granule-swizzled: granule s -> slot (s&3)*8 + (s>>2)
  int tid = threadIdx.x;
  int r0 = blockIdx.x * 128;

  #pragma unroll
  for (int q = 0; q < 16; ++q) {
    int fi = q * 1024 + tid * 4;
    int k = fi >> 7, c = fi & 127;
    float4 v = *(const float4*)&W[k * 128 + c];
    int s = c >> 2;
    int slot = ((s & 3) << 3) + (s >> 2);
    *(float4*)&Ws[k * 128 + slot * 4] = v;
  }
  __syncthreads();

  int g = tid & 7;     // col group: cols g*16 .. g*16+15
  int rg = tid >> 3;   // row group: rows rg*4 .. rg*4+3

  const float* xr[4];
  bool valid[4];
  #pragma unroll
  for (int j = 0; j < 4; ++j) {
    int R = r0 + rg * 4 + j;
    valid[j] = (R < NN);
    xr[j] = valid[j] ? &x[(size_t)R * 128] : x;
  }

  float acc[4][16];
  #pragma unroll
  for (int j = 0; j < 4; ++j)
    #pragma unroll
    for (int ii = 0; ii < 16; ++ii) acc[j][ii] = 0.f;

  for (int k = 0; k < 128; k += 4) {
    float4 xv[4];
    #pragma unroll
    for (int j = 0; j < 4; ++j) xv[j] = *(const float4*)&xr[j][k];
    #pragma unroll
    for (int t = 0; t < 4; ++t) {
      const float4* wr = (const float4*)&Ws[(k + t) * 128];
      float4 w0 = wr[g];
      float4 w1 = wr[8 + g];
      float4 w2 = wr[16 + g];
      float4 w3 = wr[24 + g];
      #pragma unroll
      for (int j = 0; j < 4; ++j) {
        float xs = ((const float*)&xv[j])[t];
        acc[j][0]  = fmaf(xs, w0.x, acc[j][0]);
        acc[j][1]  = fmaf(xs, w0.y, acc[j][1]);
        acc[j][2]  = fmaf(xs, w0.z, acc[j][2]);
        acc[j][3]  = fmaf(xs, w0.w, acc[j][3]);
        acc[j][4]  = fmaf(xs, w1.x, acc[j][4]);
        acc[j][5]  = fmaf(xs, w1.y, acc[j][5]);
        acc[j][6]  = fmaf(xs, w1.z, acc[j][6]);
        acc[j][7]  = fmaf(xs, w1.w, acc[j][7]);
        acc[j][8]  = fmaf(xs, w2.x, acc[j][8]);
        acc[j][9]  = fmaf(xs, w2.y, acc[j][9]);
        acc[j][10] = fmaf(xs, w2.z, acc[j][10]);
        acc[j][11] = fmaf(xs, w2.w, acc[j][11]);
        acc[j][12] = fmaf(xs, w3.x, acc[j][12]);
        acc[j][13] = fmaf(xs, w3.y, acc[j][13]);
        acc[j][14] = fmaf(xs, w3.z, acc[j][14]);
        acc[j][15] = fmaf(xs, w3.w, acc[j][15]);
      }
    }
  }

  int c0 = g * 16;
  float as_[16], ad_[16];
  #pragma unroll
  for (int ii = 0; ii < 16; ++ii) { as_[ii] = a_src[c0 + ii]; ad_[ii] = a_dst[c0 + ii]; }

  #pragma unroll
  for (int j = 0; j < 4; ++j) {
    int R = r0 + rg * 4 + j;
    float ps = 0.f, pd = 0.f;
    #pragma unroll
    for (int ii = 0; ii < 16; ++ii) {
      ps = fmaf(acc[j][ii], as_[ii], ps);
      pd = fmaf(acc[j][ii], ad_[ii], pd);
    }
    #pragma unroll
    for (int mdl = 1; mdl < 8; mdl <<= 1) {
      ps += __shfl_xor(ps, mdl);
      pd += __shfl_xor(pd, mdl);
    }
    if (valid[j]) {
      if (BF16OUT) {
        unsigned uu[8];
        #pragma unroll
        for (int i = 0; i < 8; ++i)
          uu[i] = (unsigned)f2bf(acc[j][2 * i]) | ((unsigned)f2bf(acc[j][2 * i + 1]) << 16);
        uint4 s0 = {uu[0], uu[1], uu[2], uu[3]};
        uint4 s1 = {uu[4], uu[5], uu[6], uu[7]};
        *(uint4*)&hb[(size_t)R * 128 + c0] = s0;
        *(uint4*)&hb[(size_t)R * 128 + c0 + 8] = s1;
      } else {
        #pragma unroll
        for (int i = 0; i < 4; ++i) {
          float4 st = {acc[j][i * 4], acc[j][i * 4 + 1], acc[j][i * 4 + 2], acc[j][i * 4 + 3]};
          *(float4*)&h[(size_t)R * 128 + c0 + i * 4] = st;
        }
      }
      if (g == 0) { alphaS[R] = ps; alphaD[R] = pd; }
    }
  }
}

// ---------------- aggregation: one wave per dst node ----------------
// BF16 path: 2 edges per inner iteration, half-wave per 256B row (uint2 = 4 bf16 per lane).

template<bool BF16, bool RELU>
__launch_bounds__(256)
__global__ void agg_kernel(const float* __restrict__ h, const unsigned short* __restrict__ hb,
                           const float* __restrict__ alphaS, const float* __restrict__ alphaD,
                           const int* __restrict__ offsets, const int* __restrict__ srcs,
                           const float* __restrict__ bias, float* __restrict__ out) {
  int lane = threadIdx.x & 63;
  int node = (blockIdx.x * 256 + threadIdx.x) >> 6;
  if (node >= NN) return;
  int beg = offsets[node], end = offsets[node + 1];
  float aD = alphaD[node];

  // pass 1: online softmax (max + sum)
  float m = -1e30f, ssum = 0.f;
  for (int j = beg + lane; j < end; j += 64) {
    int s = srcs[j];
    float e = alphaS[s] + aD;
    e = (e >= 0.f) ? e : 0.2f * e;
    if (e > m) { ssum = ssum * __expf(m - e) + 1.f; m = e; }
    else       { ssum += __expf(e - m); }
  }
  #pragma unroll
  for (int d2 = 1; d2 < 64; d2 <<= 1) {
    float mo = __shfl_xor(m, d2), so = __shfl_xor(ssum, d2);
    float mn = fmaxf(m, mo);
    ssum = ssum * __expf(m - mn) + so * __expf(mo - mn);
    m = mn;
  }
  float inv = 1.f / ssum;

  if (BF16) {
    int l2 = lane & 31, half = lane >> 5;
    float a0 = 0.f, a1 = 0.f, a2 = 0.f, a3 = 0.f;
    for (int j0 = beg; j0 < end; j0 += 64) {
      int j = j0 + lane;
      int cnt = min(64, end - j0);
      int s = 0; float wgt = 0.f;
      if (j < end) {
        int sv = srcs[j];
        float e = alphaS[sv] + aD;
        e = (e >= 0.f) ? e : 0.2f * e;
        wgt = __expf(e - m) * inv;
        s = sv;
      }
      for (int jj = 0; jj < cnt; jj += 2) {
        int e2 = jj + half;                 // lane e2's wgt is 0 if e2 >= valid count
        int sv   = __shfl(s, e2);
        float wv = __shfl(wgt, e2);
        uint2 hp = *(const uint2*)&hb[(size_t)sv * 128 + l2 * 4];
        float f0 = __uint_as_float(hp.x << 16);
        float f1 = __uint_as_float(hp.x & 0xffff0000u);
        float f2 = __uint_as_float(hp.y << 16);
        float f3 = __uint_as_float(hp.y & 0xffff0000u);
        a0 = fmaf(wv, f0, a0);
        a1 = fmaf(wv, f1, a1);
        a2 = fmaf(wv, f2, a2);
        a3 = fmaf(wv, f3, a3);
      }
    }
    a0 += __shfl_xor(a0, 32);
    a1 += __shfl_xor(a1, 32);
    a2 += __shfl_xor(a2, 32);
    a3 += __shfl_xor(a3, 32);
    if (half == 0) {
      const float4 bv = *(const float4*)&bias[l2 * 4];
      float4 o = {a0 + bv.x, a1 + bv.y, a2 + bv.z, a3 + bv.w};
      if (RELU) {
        o.x = fmaxf(o.x, 0.f); o.y = fmaxf(o.y, 0.f);
        o.z = fmaxf(o.z, 0.f); o.w = fmaxf(o.w, 0.f);
      }
      *(float4*)&out[(size_t)node * 128 + l2 * 4] = o;
    }
  } else {
    float accx = 0.f, accy = 0.f;
    for (int j0 = beg; j0 < end; j0 += 64) {
      int j = j0 + lane;
      int cnt = min(64, end - j0);
      int s = 0; float wgt = 0.f;
      if (j < end) {
        int sv = srcs[j];
        float e = alphaS[sv] + aD;
        e = (e >= 0.f) ? e : 0.2f * e;
        wgt = __expf(e - m) * inv;
        s = sv;
      }
      for (int jj = 0; jj < cnt; ++jj) {
        int sv   = __shfl(s, jj);
        float wv = __shfl(wgt, jj);
        const float2 hp = *(const float2*)&h[(size_t)sv * 128 + lane * 2];
        accx = fmaf(wv, hp.x, accx);
        accy = fmaf(wv, hp.y, accy);
      }
    }
    float ox = accx + bias[lane * 2];
    float oy = accy + bias[lane * 2 + 1];
    if (RELU) { ox = fmaxf(ox, 0.f); oy = fmaxf(oy, 0.f); }
    float2 o = {ox, oy};
    *(float2*)&out[(size_t)node * 128 + lane * 2] = o;
  }
}

// ---------------- launch ----------------

extern "C" void kernel_launch(void* const* d_in, const int* in_sizes, int n_in,
                              void* d_out, int out_size, void* d_ws, size_t ws_size,
                              hipStream_t stream) {
  const float* x   = (const float*)d_in[0];
  const int*   ei  = (const int*)d_in[1];
  const float* W0  = (const float*)d_in[2];
  const float* as0 = (const float*)d_in[3];
  const float* ad0 = (const float*)d_in[4];
  const float* b0  = (const float*)d_in[5];
  const float* W1  = (const float*)d_in[6];
  const float* as1 = (const float*)d_in[7];
  const float* ad1 = (const float*)d_in[8];
  const float* b1  = (const float*)d_in[9];
  const float* W2  = (const float*)d_in[10];
  const float* as2 = (const float*)d_in[11];
  const float* ad2 = (const float*)d_in[12];
  const float* b2  = (const float*)d_in[13];
  float* out = (float*)d_out;

  float* h      = (float*)d_ws;                    // N*128 f32 (layer 2)
  unsigned short* hb = (unsigned short*)h;         // alias: N*128 bf16 (layers 0,1)
  float* alphaS = h + (size_t)NN * 128;            // N
  float* alphaD = alphaS + NN;                     // N
  int*   counts = (int*)(alphaD + NN);             // N
  int*   offsets = counts + NN;                    // N+1
  int*   fill    = offsets + NN + 1;               // N
  int*   srcs    = fill + NN;                      // E+N

  init_counts<<<(NN + 255) / 256, 256, 0, stream>>>(counts, fill);
  count_edges<<<(EE + 255) / 256, 256, 0, stream>>>(ei + EE, counts);
  scan_offsets<<<1, 1024, 0, stream>>>(counts, offsets);
  fill_edges<<<(EE + NN + 255) / 256, 256, 0, stream>>>(ei, offsets, fill, srcs);

  const int tgrid = (NN + 127) / 128;
  const int agrid = (NN + 3) / 4;

  // layers 0,1: bf16 h for the gather; layer 2: fp32
  transform_kernel<true><<<tgrid, 256, 0, stream>>>(x, W0, as0, ad0, h, hb, alphaS, alphaD);
  agg_kernel<true, true><<<agrid, 256, 0, stream>>>(h, hb, alphaS, alphaD, offsets, srcs, b0, out);
  transform_kernel<true><<<tgrid, 256, 0, stream>>>(out, W1, as1, ad1, h, hb, alphaS, alphaD);
  agg_kernel<true, true><<<agrid, 256, 0, stream>>>(h, hb, alphaS, alphaD, offsets, srcs, b1, out);
  transform_kernel<false><<<tgrid, 256, 0, stream>>>(out, W2, as2, ad2, h, hb, alphaS, alphaD);
  agg_kernel<false, false><<<agrid, 256, 0, stream>>>(h, hb, alphaS, alphaD, offsets, srcs, b2, out);
}

// Round 3
// 516.573 us; speedup vs baseline: 1.7482x; 1.3527x over previous
//
#include <hip/hip_runtime.h>

#define NN 100000
#define EE 1600000

typedef __attribute__((ext_vector_type(8))) short bf16x8;
typedef __attribute__((ext_vector_type(4))) float f32x4;

static __device__ __forceinline__ unsigned short f2bf(float f) {
  unsigned u = __float_as_uint(f);
  u += 0x7fffu + ((u >> 16) & 1u);   // round-to-nearest-even
  return (unsigned short)(u >> 16);
}
static __device__ __forceinline__ float bf2f(unsigned short s) {
  return __uint_as_float(((unsigned)s) << 16);
}

// ---------------- CSR build ----------------

__global__ void init_counts(int* __restrict__ counts, int* __restrict__ fill) {
  int i = blockIdx.x * 256 + threadIdx.x;
  if (i < NN) { counts[i] = 1; fill[i] = 0; }   // 1 = self loop
}

__global__ void count_edges(const int* __restrict__ dst, int* __restrict__ counts) {
  int e = blockIdx.x * 256 + threadIdx.x;
  if (e < EE) atomicAdd(&counts[dst[e]], 1);
}

// single-block exclusive scan, 1024 threads x 4 elems per iter
__global__ void scan_offsets(const int* __restrict__ counts, int* __restrict__ offsets) {
  __shared__ int wsums[16];
  __shared__ int carryS;
  int tid = threadIdx.x, lane = tid & 63, wid = tid >> 6;
  if (tid == 0) carryS = 0;
  __syncthreads();
  for (int base = 0; base < NN; base += 4096) {
    int i0 = base + tid * 4;
    int4 v = {0, 0, 0, 0};
    if (i0 < NN) v = *(const int4*)&counts[i0];   // NN % 4 == 0, so all-or-none
    int tsum = v.x + v.y + v.z + v.w;
    int x = tsum;
    #pragma unroll
    for (int d = 1; d < 64; d <<= 1) { int y = __shfl_up(x, d); if (lane >= d) x += y; }
    if (lane == 63) wsums[wid] = x;
    __syncthreads();
    if (tid < 16) {
      int s = wsums[tid];
      #pragma unroll
      for (int d = 1; d < 16; d <<= 1) { int y = __shfl_up(s, d); if (tid >= d) s += y; }
      wsums[tid] = s;
    }
    __syncthreads();
    int carry = carryS;
    int wbase = (wid == 0) ? 0 : wsums[wid - 1];
    int excl = carry + wbase + (x - tsum);
    if (i0 < NN) {
      int4 o;
      o.x = excl;
      o.y = o.x + v.x;
      o.z = o.y + v.y;
      o.w = o.z + v.z;
      *(int4*)&offsets[i0] = o;
    }
    int total = wsums[15];
    __syncthreads();
    if (tid == 0) carryS = carry + total;
    __syncthreads();
  }
  if (tid == 0) offsets[NN] = carryS;
}

__global__ void fill_edges(const int* __restrict__ ei, const int* __restrict__ offsets,
                           int* __restrict__ fill, int* __restrict__ srcs) {
  int idx = blockIdx.x * 256 + threadIdx.x;
  if (idx >= EE + NN) return;
  int s, d;
  if (idx < EE) { s = ei[idx]; d = ei[EE + idx]; }
  else          { s = d = idx - EE; }            // self loop
  int p = atomicAdd(&fill[d], 1);
  srcs[offsets[d] + p] = s;
}

// ---------------- W prep: fragment-ordered bf16 hi/lo split ----------------
// B-frag for 16x16x32: lane l elem i -> W[kt*32 + (l>>4)*8 + i][ct*16 + (l&15)]
// stored at [((kt*8+ct)*64 + l)*8 + i]

__global__ void prep_w(const float* __restrict__ W, short* __restrict__ Whi,
                       short* __restrict__ Wlo) {
  int t = blockIdx.x * 256 + threadIdx.x;   // 2048 threads total
  if (t >= 2048) return;
  int lane = t & 63, ct = (t >> 6) & 7, kt = t >> 9;
  int l4 = lane & 15, grp = lane >> 4;
  int c = ct * 16 + l4;
  int k0 = kt * 32 + grp * 8;
  bf16x8 hi, lo;
  #pragma unroll
  for (int i = 0; i < 8; ++i) {
    float w = W[(k0 + i) * 128 + c];
    unsigned short h = f2bf(w);
    hi[i] = (short)h;
    lo[i] = (short)f2bf(w - bf2f(h));
  }
  size_t off = ((size_t)(kt * 8 + ct) * 64 + lane) * 8;
  *(bf16x8*)&Whi[off] = hi;
  *(bf16x8*)&Wlo[off] = lo;
}

// ---------------- transform: h = x @ W (3-term split-bf16 MFMA), alphas exact ----------------
// 256 threads = 4 waves; block tile 128 rows; wave tile 32 rows x 128 cols
// per wave: 2 row-tiles x 8 col-tiles of 16x16, K = 4 steps of 32.

__launch_bounds__(256, 2)
__global__ void transform_mfma(const float* __restrict__ x,
                               const short* __restrict__ Whi, const short* __restrict__ Wlo,
                               const float* __restrict__ a_src, const float* __restrict__ a_dst,
                               unsigned short* __restrict__ hb,
                               float* __restrict__ alphaS, float* __restrict__ alphaD) {
  int tid = threadIdx.x;
  int lane = tid & 63, wid = tid >> 6;
  int l4 = lane & 15, grp = lane >> 4;
  int rbase = blockIdx.x * 128 + wid * 32;

  const float* xr[2];
  #pragma unroll
  for (int rt = 0; rt < 2; ++rt) {
    int R = rbase + rt * 16 + l4;
    xr[rt] = x + (size_t)(R < NN ? R : 0) * 128;
  }

  f32x4 acc[2][8];
  #pragma unroll
  for (int rt = 0; rt < 2; ++rt)
    #pragma unroll
    for (int ct = 0; ct < 8; ++ct) acc[rt][ct] = (f32x4)(0.f);

  #pragma unroll
  for (int kt = 0; kt < 4; ++kt) {
    bf16x8 Ahi[2], Alo[2];
    #pragma unroll
    for (int rt = 0; rt < 2; ++rt) {
      const float* p = xr[rt] + kt * 32 + grp * 8;
      float4 v0 = *(const float4*)p;
      float4 v1 = *(const float4*)(p + 4);
      float f[8] = {v0.x, v0.y, v0.z, v0.w, v1.x, v1.y, v1.z, v1.w};
      #pragma unroll
      for (int i = 0; i < 8; ++i) {
        unsigned short h = f2bf(f[i]);
        Ahi[rt][i] = (short)h;
        Alo[rt][i] = (short)f2bf(f[i] - bf2f(h));
      }
    }
    #pragma unroll
    for (int ct = 0; ct < 8; ++ct) {
      size_t off = ((size_t)(kt * 8 + ct) * 64 + lane) * 8;
      bf16x8 bh = *(const bf16x8*)&Whi[off];
      bf16x8 bl = *(const bf16x8*)&Wlo[off];
      #pragma unroll
      for (int rt = 0; rt < 2; ++rt) {
        acc[rt][ct] = __builtin_amdgcn_mfma_f32_16x16x32_bf16(Ahi[rt], bh, acc[rt][ct], 0, 0, 0);
        acc[rt][ct] = __builtin_amdgcn_mfma_f32_16x16x32_bf16(Ahi[rt], bl, acc[rt][ct], 0, 0, 0);
        acc[rt][ct] = __builtin_amdgcn_mfma_f32_16x16x32_bf16(Alo[rt], bh, acc[rt][ct], 0, 0, 0);
      }
    }
  }

  // alphas from fp32 accumulators (exact w.r.t. stored h)
  float asv[8], adv[8];
  #pragma unroll
  for (int ct = 0; ct < 8; ++ct) { asv[ct] = a_src[ct * 16 + l4]; adv[ct] = a_dst[ct * 16 + l4]; }

  #pragma unroll
  for (int rt = 0; rt < 2; ++rt) {
    #pragma unroll
    for (int reg = 0; reg < 4; ++reg) {
      float ps = 0.f, pd = 0.f;
      #pragma unroll
      for (int ct = 0; ct < 8; ++ct) {
        ps = fmaf(acc[rt][ct][reg], asv[ct], ps);
        pd = fmaf(acc[rt][ct][reg], adv[ct], pd);
      }
      #pragma unroll
      for (int mdl = 1; mdl < 16; mdl <<= 1) {
        ps += __shfl_xor(ps, mdl);
        pd += __shfl_xor(pd, mdl);
      }
      int row = rbase + rt * 16 + grp * 4 + reg;
      if (l4 == 0 && row < NN) { alphaS[row] = ps; alphaD[row] = pd; }
    }
    // h store (bf16), C layout: col = ct*16 + l4, row = rbase + rt*16 + grp*4 + reg
    #pragma unroll
    for (int reg = 0; reg < 4; ++reg) {
      int row = rbase + rt * 16 + grp * 4 + reg;
      if (row < NN) {
        #pragma unroll
        for (int ct = 0; ct < 8; ++ct)
          hb[(size_t)row * 128 + ct * 16 + l4] = f2bf(acc[rt][ct][reg]);
      }
    }
  }
}

// ---------------- aggregation: one wave per dst node, 4 edges/iter (uint4/lane) ----------------

template<bool RELU>
__launch_bounds__(256)
__global__ void agg_kernel(const unsigned short* __restrict__ hb,
                           const float* __restrict__ alphaS, const float* __restrict__ alphaD,
                           const int* __restrict__ offsets, const int* __restrict__ srcs,
                           const float* __restrict__ bias, float* __restrict__ out) {
  int lane = threadIdx.x & 63;
  int node = (blockIdx.x * 256 + threadIdx.x) >> 6;
  if (node >= NN) return;
  int beg = offsets[node], end = offsets[node + 1];
  float aD = alphaD[node];

  // pass 1: online softmax (max + sum)
  float m = -1e30f, ssum = 0.f;
  for (int j = beg + lane; j < end; j += 64) {
    int s = srcs[j];
    float e = alphaS[s] + aD;
    e = (e >= 0.f) ? e : 0.2f * e;
    if (e > m) { ssum = ssum * __expf(m - e) + 1.f; m = e; }
    else       { ssum += __expf(e - m); }
  }
  #pragma unroll
  for (int d2 = 1; d2 < 64; d2 <<= 1) {
    float mo = __shfl_xor(m, d2), so = __shfl_xor(ssum, d2);
    float mn = fmaxf(m, mo);
    ssum = ssum * __expf(m - mn) + so * __expf(mo - mn);
    m = mn;
  }
  float inv = 1.f / ssum;

  // pass 2: weighted gather; 16 lanes per 256B row, 4 edges per iteration
  int l4 = lane & 15, grp = lane >> 4;
  float a[8];
  #pragma unroll
  for (int i = 0; i < 8; ++i) a[i] = 0.f;

  for (int j0 = beg; j0 < end; j0 += 64) {
    int j = j0 + lane;
    int cnt = min(64, end - j0);
    int s = 0; float wgt = 0.f;
    if (j < end) {
      int sv = srcs[j];
      float e = alphaS[sv] + aD;
      e = (e >= 0.f) ? e : 0.2f * e;
      wgt = __expf(e - m) * inv;
      s = sv;
    }
    for (int jj = 0; jj < cnt; jj += 4) {
      int e2 = jj + grp;              // <= 63 always; lanes past cnt carry wgt = 0
      int sv   = __shfl(s, e2);
      float wv = __shfl(wgt, e2);
      uint4 hp = *(const uint4*)&hb[(size_t)sv * 128 + l4 * 8];
      a[0] = fmaf(wv, __uint_as_float(hp.x << 16),           a[0]);
      a[1] = fmaf(wv, __uint_as_float(hp.x & 0xffff0000u),   a[1]);
      a[2] = fmaf(wv, __uint_as_float(hp.y << 16),           a[2]);
      a[3] = fmaf(wv, __uint_as_float(hp.y & 0xffff0000u),   a[3]);
      a[4] = fmaf(wv, __uint_as_float(hp.z << 16),           a[4]);
      a[5] = fmaf(wv, __uint_as_float(hp.z & 0xffff0000u),   a[5]);
      a[6] = fmaf(wv, __uint_as_float(hp.w << 16),           a[6]);
      a[7] = fmaf(wv, __uint_as_float(hp.w & 0xffff0000u),   a[7]);
    }
  }
  #pragma unroll
  for (int i = 0; i < 8; ++i) {
    a[i] += __shfl_xor(a[i], 16);
    a[i] += __shfl_xor(a[i], 32);
  }
  if (grp == 0) {
    float4 b0 = *(const float4*)&bias[l4 * 8];
    float4 b1 = *(const float4*)&bias[l4 * 8 + 4];
    float4 o0 = {a[0] + b0.x, a[1] + b0.y, a[2] + b0.z, a[3] + b0.w};
    float4 o1 = {a[4] + b1.x, a[5] + b1.y, a[6] + b1.z, a[7] + b1.w};
    if (RELU) {
      o0.x = fmaxf(o0.x, 0.f); o0.y = fmaxf(o0.y, 0.f);
      o0.z = fmaxf(o0.z, 0.f); o0.w = fmaxf(o0.w, 0.f);
      o1.x = fmaxf(o1.x, 0.f); o1.y = fmaxf(o1.y, 0.f);
      o1.z = fmaxf(o1.z, 0.f); o1.w = fmaxf(o1.w, 0.f);
    }
    *(float4*)&out[(size_t)node * 128 + l4 * 8]     = o0;
    *(float4*)&out[(size_t)node * 128 + l4 * 8 + 4] = o1;
  }
}

// ---------------- launch ----------------

extern "C" void kernel_launch(void* const* d_in, const int* in_sizes, int n_in,
                              void* d_out, int out_size, void* d_ws, size_t ws_size,
                              hipStream_t stream) {
  const float* x   = (const float*)d_in[0];
  const int*   ei  = (const int*)d_in[1];
  const float* W0  = (const float*)d_in[2];
  const float* as0 = (const float*)d_in[3];
  const float* ad0 = (const float*)d_in[4];
  const float* b0  = (const float*)d_in[5];
  const float* W1  = (const float*)d_in[6];
  const float* as1 = (const float*)d_in[7];
  const float* ad1 = (const float*)d_in[8];
  const float* b1  = (const float*)d_in[9];
  const float* W2  = (const float*)d_in[10];
  const float* as2 = (const float*)d_in[11];
  const float* ad2 = (const float*)d_in[12];
  const float* b2  = (const float*)d_in[13];
  float* out = (float*)d_out;

  short* Whi = (short*)d_ws;                                 // 16384 (16B-aligned)
  short* Wlo = Whi + 16384;                                  // 16384
  unsigned short* hb = (unsigned short*)(Wlo + 16384);       // N*128 bf16
  float* alphaS = (float*)(hb + (size_t)NN * 128);           // N
  float* alphaD = alphaS + NN;                               // N
  int*   counts = (int*)(alphaD + NN);                       // N
  int*   offsets = counts + NN;                              // N+1
  int*   fill    = offsets + NN + 1;                         // N
  int*   srcs    = fill + NN;                                // E+N

  init_counts<<<(NN + 255) / 256, 256, 0, stream>>>(counts, fill);
  count_edges<<<(EE + 255) / 256, 256, 0, stream>>>(ei + EE, counts);
  scan_offsets<<<1, 1024, 0, stream>>>(counts, offsets);
  fill_edges<<<(EE + NN + 255) / 256, 256, 0, stream>>>(ei, offsets, fill, srcs);

  const int tgrid = (NN + 127) / 128;
  const int agrid = (NN + 3) / 4;

  prep_w<<<8, 256, 0, stream>>>(W0, Whi, Wlo);
  transform_mfma<<<tgrid, 256, 0, stream>>>(x, Whi, Wlo, as0, ad0, hb, alphaS, alphaD);
  agg_kernel<true><<<agrid, 256, 0, stream>>>(hb, alphaS, alphaD, offsets, srcs, b0, out);

  prep_w<<<8, 256, 0, stream>>>(W1, Whi, Wlo);
  transform_mfma<<<tgrid, 256, 0, stream>>>(out, Whi, Wlo, as1, ad1, hb, alphaS, alphaD);
  agg_kernel<true><<<agrid, 256, 0, stream>>>(hb, alphaS, alphaD, offsets, srcs, b1, out);

  prep_w<<<8, 256, 0, stream>>>(W2, Whi, Wlo);
  transform_mfma<<<tgrid, 256, 0, stream>>>(out, Whi, Wlo, as2, ad2, hb, alphaS, alphaD);
  agg_kernel<false><<<agrid, 256, 0, stream>>>(hb, alphaS, alphaD, offsets, srcs, b2, out);
}

// Round 5
// 397.985 us; speedup vs baseline: 2.2692x; 1.2980x over previous
//
#include <hip/hip_runtime.h>

#define NN 100000
#define EE 1600000
#define NB 391          // buckets of 256 dst nodes: ceil(100000/256)
#define CHUNK 2048

typedef __attribute__((ext_vector_type(8))) short bf16x8;
typedef __attribute__((ext_vector_type(4))) float f32x4;

static __device__ __forceinline__ unsigned short f2bf(float f) {
  unsigned u = __float_as_uint(f);
  u += 0x7fffu + ((u >> 16) & 1u);   // round-to-nearest-even
  return (unsigned short)(u >> 16);
}
static __device__ __forceinline__ float bf2f(unsigned short s) {
  return __uint_as_float(((unsigned)s) << 16);
}

// ---------------- CSR build: two-level counting sort ----------------

__global__ void zero_aux(int* __restrict__ bcnt, int* __restrict__ bfill) {
  int i = blockIdx.x * 256 + threadIdx.x;
  if (i < NB * 16) { bcnt[i] = 0; bfill[i] = 0; }
}

// Phase A: coarse-bucket histogram (LDS-aggregated, padded global merge)
__launch_bounds__(256)
__global__ void bucket_hist(const int* __restrict__ dst, int* __restrict__ bcnt) {
  __shared__ int hist[NB];
  int tid = threadIdx.x;
  for (int i = tid; i < NB; i += 256) hist[i] = 0;
  __syncthreads();
  int e0 = blockIdx.x * CHUNK;
  int n = min(CHUNK, EE - e0);
  for (int i = tid; i < n; i += 256) atomicAdd(&hist[dst[e0 + i] >> 8], 1);
  __syncthreads();
  for (int i = tid; i < NB; i += 256) {
    int c = hist[i];
    if (c) atomicAdd(&bcnt[i * 16], c);
  }
}

// Phase B: scan bucket counts -> bOffC; also offsets[NN]
__launch_bounds__(256)
__global__ void bucket_scan(const int* __restrict__ bcnt, int* __restrict__ bOffC,
                            int* __restrict__ offsets) {
  __shared__ int wpart[4];
  __shared__ int carryS;
  int tid = threadIdx.x, lane = tid & 63, w = tid >> 6;
  if (tid == 0) carryS = 0;
  __syncthreads();
  for (int base = 0; base < NB; base += 256) {
    int i = base + tid;
    int v = (i < NB) ? bcnt[i * 16] : 0;
    int x = v;
    #pragma unroll
    for (int d = 1; d < 64; d <<= 1) { int y = __shfl_up(x, d); if (lane >= d) x += y; }
    if (lane == 63) wpart[w] = x;
    __syncthreads();
    int wbase = 0;
    #pragma unroll
    for (int k = 0; k < 3; ++k) if (k < w) wbase += wpart[k];
    int tot = wpart[0] + wpart[1] + wpart[2] + wpart[3];
    int carry = carryS;
    if (i < NB) bOffC[i] = carry + wbase + x - v;
    __syncthreads();
    if (tid == 0) carryS = carry + tot;
    __syncthreads();
  }
  if (tid == 0) offsets[NN] = EE + NN;
}

// Phase C: bucket-sorted scatter of (s,d) pairs via LDS staging
__launch_bounds__(256)
__global__ void bucket_scatter(const int* __restrict__ ei, const int* __restrict__ bOffC,
                               int* __restrict__ bfill, long long* __restrict__ pairs) {
  __shared__ int hist[NB];
  __shared__ int lofs[NB];
  __shared__ int resv[NB];
  __shared__ long long stage[CHUNK];
  __shared__ int wpart[4];
  int tid = threadIdx.x, lane = tid & 63, w = tid >> 6;
  int e0 = blockIdx.x * CHUNK;
  int n = min(CHUNK, EE - e0);
  for (int i = tid; i < NB; i += 256) hist[i] = 0;
  __syncthreads();

  int s[8], d[8], lp[8], bk[8];
  #pragma unroll
  for (int q = 0; q < 8; ++q) {
    int i = q * 256 + tid;
    if (i < n) {
      s[q] = ei[e0 + i];
      d[q] = ei[EE + e0 + i];
      bk[q] = d[q] >> 8;
      lp[q] = atomicAdd(&hist[bk[q]], 1);
    }
  }
  __syncthreads();

  // exclusive scan hist -> lofs
  int carry = 0;
  for (int base = 0; base < NB; base += 256) {
    int i = base + tid;
    int v = (i < NB) ? hist[i] : 0;
    int x = v;
    #pragma unroll
    for (int dd = 1; dd < 64; dd <<= 1) { int y = __shfl_up(x, dd); if (lane >= dd) x += y; }
    if (lane == 63) wpart[w] = x;
    __syncthreads();
    int wbase = 0;
    #pragma unroll
    for (int k = 0; k < 3; ++k) if (k < w) wbase += wpart[k];
    int tot = wpart[0] + wpart[1] + wpart[2] + wpart[3];
    if (i < NB) lofs[i] = carry + wbase + x - v;
    __syncthreads();
    carry += tot;
  }

  // stage pairs bucket-sorted in LDS
  #pragma unroll
  for (int q = 0; q < 8; ++q) {
    int i = q * 256 + tid;
    if (i < n) stage[lofs[bk[q]] + lp[q]] = ((long long)d[q] << 32) | (unsigned)s[q];
  }
  // reserve global runs (one atomic per non-empty bucket)
  for (int b = tid; b < NB; b += 256) {
    int c = hist[b];
    resv[b] = c ? atomicAdd(&bfill[b * 16], c) : 0;
  }
  __syncthreads();
  // write runs (coalesced within runs)
  for (int i = tid; i < n; i += 256) {
    long long pd = stage[i];
    int dd = (int)(pd >> 32);
    int b = dd >> 8;
    pairs[(size_t)bOffC[b] + resv[b] + (i - lofs[b])] = pd;
  }
}

// Phase D: per-bucket fine CSR build (LDS counters, L2-local scatter, self-loops)
__launch_bounds__(256)
__global__ void build_csr(const long long* __restrict__ pairs, const int* __restrict__ bOffC,
                          const int* __restrict__ bcnt, int* __restrict__ offsets,
                          int* __restrict__ srcs) {
  __shared__ int deg[256];
  __shared__ int intra[256];
  __shared__ int fil[256];
  __shared__ int wpart[4];
  int b = blockIdx.x, tid = threadIdx.x;
  int n0 = b << 8;
  int nodes = min(256, NN - n0);
  int ecnt = bcnt[b * 16];
  size_t pbase = (size_t)bOffC[b];
  int cbase = bOffC[b] + n0;        // + n0 self-loops from earlier buckets
  deg[tid] = 0; fil[tid] = 0;
  __syncthreads();
  for (int i = tid; i < ecnt; i += 256) {
    int dd = (int)(pairs[pbase + i] >> 32);
    atomicAdd(&deg[dd - n0], 1);
  }
  __syncthreads();
  int v = (tid < nodes) ? deg[tid] + 1 : 0;   // +1 self-loop
  int lane = tid & 63, w = tid >> 6;
  int x = v;
  #pragma unroll
  for (int dd = 1; dd < 64; dd <<= 1) { int y = __shfl_up(x, dd); if (lane >= dd) x += y; }
  if (lane == 63) wpart[w] = x;
  __syncthreads();
  int wbase = 0;
  #pragma unroll
  for (int k = 0; k < 3; ++k) if (k < w) wbase += wpart[k];
  int excl = wbase + x - v;
  if (tid < nodes) { intra[tid] = excl; offsets[n0 + tid] = cbase + excl; }
  __syncthreads();
  for (int i = tid; i < ecnt; i += 256) {
    long long pd = pairs[pbase + i];
    int dd = (int)(pd >> 32), ss = (int)pd;
    int ln = dd - n0;
    int p = atomicAdd(&fil[ln], 1);
    srcs[cbase + intra[ln] + p] = ss;
  }
  __syncthreads();
  if (tid < nodes) srcs[cbase + intra[tid] + deg[tid]] = n0 + tid;   // self-loop last
}

// ---------------- W prep: fragment-ordered bf16 hi/lo split ----------------

__global__ void prep_w(const float* __restrict__ W, short* __restrict__ Whi,
                       short* __restrict__ Wlo) {
  int t = blockIdx.x * 256 + threadIdx.x;
  if (t >= 2048) return;
  int lane = t & 63, ct = (t >> 6) & 7, kt = t >> 9;
  int l4 = lane & 15, grp = lane >> 4;
  int c = ct * 16 + l4;
  int k0 = kt * 32 + grp * 8;
  bf16x8 hi, lo;
  #pragma unroll
  for (int i = 0; i < 8; ++i) {
    float w = W[(k0 + i) * 128 + c];
    unsigned short h = f2bf(w);
    hi[i] = (short)h;
    lo[i] = (short)f2bf(w - bf2f(h));
  }
  size_t off = ((size_t)(kt * 8 + ct) * 64 + lane) * 8;
  *(bf16x8*)&Whi[off] = hi;
  *(bf16x8*)&Wlo[off] = lo;
}

// ---------------- transform: h = x @ W (3-term split-bf16 MFMA) ----------------

__launch_bounds__(256, 2)
__global__ void transform_mfma(const float* __restrict__ x,
                               const short* __restrict__ Whi, const short* __restrict__ Wlo,
                               const float* __restrict__ a_src, const float* __restrict__ a_dst,
                               unsigned short* __restrict__ hb,
                               float* __restrict__ alphaS, float* __restrict__ alphaD) {
  int tid = threadIdx.x;
  int lane = tid & 63, wid = tid >> 6;
  int l4 = lane & 15, grp = lane >> 4;
  int rbase = blockIdx.x * 128 + wid * 32;

  const float* xr[2];
  #pragma unroll
  for (int rt = 0; rt < 2; ++rt) {
    int R = rbase + rt * 16 + l4;
    xr[rt] = x + (size_t)(R < NN ? R : 0) * 128;
  }

  f32x4 acc[2][8];
  #pragma unroll
  for (int rt = 0; rt < 2; ++rt)
    #pragma unroll
    for (int ct = 0; ct < 8; ++ct) acc[rt][ct] = (f32x4)(0.f);

  #pragma unroll
  for (int kt = 0; kt < 4; ++kt) {
    bf16x8 Ahi[2], Alo[2];
    #pragma unroll
    for (int rt = 0; rt < 2; ++rt) {
      const float* p = xr[rt] + kt * 32 + grp * 8;
      float4 v0 = *(const float4*)p;
      float4 v1 = *(const float4*)(p + 4);
      float f[8] = {v0.x, v0.y, v0.z, v0.w, v1.x, v1.y, v1.z, v1.w};
      #pragma unroll
      for (int i = 0; i < 8; ++i) {
        unsigned short h = f2bf(f[i]);
        Ahi[rt][i] = (short)h;
        Alo[rt][i] = (short)f2bf(f[i] - bf2f(h));
      }
    }
    #pragma unroll
    for (int ct = 0; ct < 8; ++ct) {
      size_t off = ((size_t)(kt * 8 + ct) * 64 + lane) * 8;
      bf16x8 bh = *(const bf16x8*)&Whi[off];
      bf16x8 bl = *(const bf16x8*)&Wlo[off];
      #pragma unroll
      for (int rt = 0; rt < 2; ++rt) {
        acc[rt][ct] = __builtin_amdgcn_mfma_f32_16x16x32_bf16(Ahi[rt], bh, acc[rt][ct], 0, 0, 0);
        acc[rt][ct] = __builtin_amdgcn_mfma_f32_16x16x32_bf16(Ahi[rt], bl, acc[rt][ct], 0, 0, 0);
        acc[rt][ct] = __builtin_amdgcn_mfma_f32_16x16x32_bf16(Alo[rt], bh, acc[rt][ct], 0, 0, 0);
      }
    }
  }

  float asv[8], adv[8];
  #pragma unroll
  for (int ct = 0; ct < 8; ++ct) { asv[ct] = a_src[ct * 16 + l4]; adv[ct] = a_dst[ct * 16 + l4]; }

  #pragma unroll
  for (int rt = 0; rt < 2; ++rt) {
    #pragma unroll
    for (int reg = 0; reg < 4; ++reg) {
      float ps = 0.f, pd = 0.f;
      #pragma unroll
      for (int ct = 0; ct < 8; ++ct) {
        ps = fmaf(acc[rt][ct][reg], asv[ct], ps);
        pd = fmaf(acc[rt][ct][reg], adv[ct], pd);
      }
      #pragma unroll
      for (int mdl = 1; mdl < 16; mdl <<= 1) {
        ps += __shfl_xor(ps, mdl);
        pd += __shfl_xor(pd, mdl);
      }
      int row = rbase + rt * 16 + grp * 4 + reg;
      if (l4 == 0 && row < NN) { alphaS[row] = ps; alphaD[row] = pd; }
    }
    #pragma unroll
    for (int reg = 0; reg < 4; ++reg) {
      int row = rbase + rt * 16 + grp * 4 + reg;
      if (row < NN) {
        #pragma unroll
        for (int ct = 0; ct < 8; ++ct)
          hb[(size_t)row * 128 + ct * 16 + l4] = f2bf(acc[rt][ct][reg]);
      }
    }
  }
}

// ---------------- aggregation: one wave per dst node, 4 edges/iter ----------------

template<bool RELU>
__launch_bounds__(256)
__global__ void agg_kernel(const unsigned short* __restrict__ hb,
                           const float* __restrict__ alphaS, const float* __restrict__ alphaD,
                           const int* __restrict__ offsets, const int* __restrict__ srcs,
                           const float* __restrict__ bias, float* __restrict__ out) {
  int lane = threadIdx.x & 63;
  int node = (blockIdx.x * 256 + threadIdx.x) >> 6;
  if (node >= NN) return;
  int beg = offsets[node], end = offsets[node + 1];
  float aD = alphaD[node];

  float m = -1e30f, ssum = 0.f;
  for (int j = beg + lane; j < end; j += 64) {
    int s = srcs[j];
    float e = alphaS[s] + aD;
    e = (e >= 0.f) ? e : 0.2f * e;
    if (e > m) { ssum = ssum * __expf(m - e) + 1.f; m = e; }
    else       { ssum += __expf(e - m); }
  }
  #pragma unroll
  for (int d2 = 1; d2 < 64; d2 <<= 1) {
    float mo = __shfl_xor(m, d2), so = __shfl_xor(ssum, d2);
    float mn = fmaxf(m, mo);
    ssum = ssum * __expf(m - mn) + so * __expf(mo - mn);
    m = mn;
  }
  float inv = 1.f / ssum;

  int l4 = lane & 15, grp = lane >> 4;
  float a[8];
  #pragma unroll
  for (int i = 0; i < 8; ++i) a[i] = 0.f;

  for (int j0 = beg; j0 < end; j0 += 64) {
    int j = j0 + lane;
    int cnt = min(64, end - j0);
    int s = 0; float wgt = 0.f;
    if (j < end) {
      int sv = srcs[j];
      float e = alphaS[sv] + aD;
      e = (e >= 0.f) ? e : 0.2f * e;
      wgt = __expf(e - m) * inv;
      s = sv;
    }
    for (int jj = 0; jj < cnt; jj += 4) {
      int e2 = jj + grp;
      int sv   = __shfl(s, e2);
      float wv = __shfl(wgt, e2);
      uint4 hp = *(const uint4*)&hb[(size_t)sv * 128 + l4 * 8];
      a[0] = fmaf(wv, __uint_as_float(hp.x << 16),           a[0]);
      a[1] = fmaf(wv, __uint_as_float(hp.x & 0xffff0000u),   a[1]);
      a[2] = fmaf(wv, __uint_as_float(hp.y << 16),           a[2]);
      a[3] = fmaf(wv, __uint_as_float(hp.y & 0xffff0000u),   a[3]);
      a[4] = fmaf(wv, __uint_as_float(hp.z << 16),           a[4]);
      a[5] = fmaf(wv, __uint_as_float(hp.z & 0xffff0000u),   a[5]);
      a[6] = fmaf(wv, __uint_as_float(hp.w << 16),           a[6]);
      a[7] = fmaf(wv, __uint_as_float(hp.w & 0xffff0000u),   a[7]);
    }
  }
  #pragma unroll
  for (int i = 0; i < 8; ++i) {
    a[i] += __shfl_xor(a[i], 16);
    a[i] += __shfl_xor(a[i], 32);
  }
  if (grp == 0) {
    float4 b0 = *(const float4*)&bias[l4 * 8];
    float4 b1 = *(const float4*)&bias[l4 * 8 + 4];
    float4 o0 = {a[0] + b0.x, a[1] + b0.y, a[2] + b0.z, a[3] + b0.w};
    float4 o1 = {a[4] + b1.x, a[5] + b1.y, a[6] + b1.z, a[7] + b1.w};
    if (RELU) {
      o0.x = fmaxf(o0.x, 0.f); o0.y = fmaxf(o0.y, 0.f);
      o0.z = fmaxf(o0.z, 0.f); o0.w = fmaxf(o0.w, 0.f);
      o1.x = fmaxf(o1.x, 0.f); o1.y = fmaxf(o1.y, 0.f);
      o1.z = fmaxf(o1.z, 0.f); o1.w = fmaxf(o1.w, 0.f);
    }
    *(float4*)&out[(size_t)node * 128 + l4 * 8]     = o0;
    *(float4*)&out[(size_t)node * 128 + l4 * 8 + 4] = o1;
  }
}

// ---------------- launch ----------------

extern "C" void kernel_launch(void* const* d_in, const int* in_sizes, int n_in,
                              void* d_out, int out_size, void* d_ws, size_t ws_size,
                              hipStream_t stream) {
  const float* x   = (const float*)d_in[0];
  const int*   ei  = (const int*)d_in[1];
  const float* W0  = (const float*)d_in[2];
  const float* as0 = (const float*)d_in[3];
  const float* ad0 = (const float*)d_in[4];
  const float* b0  = (const float*)d_in[5];
  const float* W1  = (const float*)d_in[6];
  const float* as1 = (const float*)d_in[7];
  const float* ad1 = (const float*)d_in[8];
  const float* b1  = (const float*)d_in[9];
  const float* W2  = (const float*)d_in[10];
  const float* as2 = (const float*)d_in[11];
  const float* ad2 = (const float*)d_in[12];
  const float* b2  = (const float*)d_in[13];
  float* out = (float*)d_out;

  long long* pairs = (long long*)d_ws;                         // E (8B-aligned first)
  short* Whi = (short*)(pairs + EE);                           // 16384
  short* Wlo = Whi + 16384;                                    // 16384
  unsigned short* hb = (unsigned short*)(Wlo + 16384);         // N*128
  float* alphaS = (float*)(hb + (size_t)NN * 128);             // N
  float* alphaD = alphaS + NN;                                 // N
  int*   offsets = (int*)(alphaD + NN);                        // N+1
  int*   srcs    = offsets + NN + 1;                           // E+N
  int*   bcnt    = srcs + EE + NN;                             // NB*16 (padded)
  int*   bfill   = bcnt + NB * 16;                             // NB*16
  int*   bOffC   = bfill + NB * 16;                            // NB

  const int cgrid = (EE + CHUNK - 1) / CHUNK;   // 782

  zero_aux<<<(NB * 16 + 255) / 256, 256, 0, stream>>>(bcnt, bfill);
  bucket_hist<<<cgrid, 256, 0, stream>>>(ei + EE, bcnt);
  bucket_scan<<<1, 256, 0, stream>>>(bcnt, bOffC, offsets);
  bucket_scatter<<<cgrid, 256, 0, stream>>>(ei, bOffC, bfill, pairs);
  build_csr<<<NB, 256, 0, stream>>>(pairs, bOffC, bcnt, offsets, srcs);

  const int tgrid = (NN + 127) / 128;
  const int agrid = (NN + 3) / 4;

  prep_w<<<8, 256, 0, stream>>>(W0, Whi, Wlo);
  transform_mfma<<<tgrid, 256, 0, stream>>>(x, Whi, Wlo, as0, ad0, hb, alphaS, alphaD);
  agg_kernel<true><<<agrid, 256, 0, stream>>>(hb, alphaS, alphaD, offsets, srcs, b0, out);

  prep_w<<<8, 256, 0, stream>>>(W1, Whi, Wlo);
  transform_mfma<<<tgrid, 256, 0, stream>>>(out, Whi, Wlo, as1, ad1, hb, alphaS, alphaD);
  agg_kernel<true><<<agrid, 256, 0, stream>>>(hb, alphaS, alphaD, offsets, srcs, b1, out);

  prep_w<<<8, 256, 0, stream>>>(W2, Whi, Wlo);
  transform_mfma<<<tgrid, 256, 0, stream>>>(out, Whi, Wlo, as2, ad2, hb, alphaS, alphaD);
  agg_kernel<false><<<agrid, 256, 0, stream>>>(hb, alphaS, alphaD, offsets, srcs, b2, out);
}